// Round 1
// 723.661 us; speedup vs baseline: 1.1112x; 1.1112x over previous
//
#include <hip/hip_runtime.h>

#define N_NODES 100000
#define N_EDGES 3200000
#define D 256
#define NBLK ((N_NODES + 255) / 256)     // 391 scan blocks
#define GEMM_TILES (N_NODES / 32)        // 3125 tiles of 32 rows
#define GEMM_BLOCKS ((GEMM_TILES + 3) / 4)  // 782
#define HIST_BLOCKS (N_EDGES / 256)      // 12500
#define ZERO_BLOCKS NBLK                 // 391
#define WSH_BLOCKS 32

#define RPB 16                           // rows per bucket
#define NB_BUCKETS (N_NODES / RPB)       // 6250 (exact)
#define P2_CAP 4096                      // LDS entry cap (mean 512, 30+ sigma)

using u16 = unsigned short;
using u32 = unsigned int;

typedef __attribute__((ext_vector_type(8))) short bf16x8;
typedef __attribute__((ext_vector_type(4))) float f32x4;

__device__ inline u16 f2bf(float f) {
    u32 x = __builtin_bit_cast(u32, f);
    return (u16)((x + 0x7FFFu + ((x >> 16) & 1u)) >> 16);
}
__device__ inline float bf2f(u16 u) {
    return __builtin_bit_cast(float, (u32)u << 16);
}

// -------- prep: zero cnt (blocks 0..390) + W shuffle (blocks 391..422) -----
// Wf layout [kt(8)][nt(16)][lane(64)][j(8)]:
//   b[j] = W[kt*32 + (lane>>4)*8 + j][nt*16 + (lane&15)]
__global__ __launch_bounds__(256) void prep_kernel(
    const float* __restrict__ W, u16* __restrict__ Wf, int* __restrict__ cnt)
{
    if (blockIdx.x < ZERO_BLOCKS) {
        const int i = blockIdx.x * 256 + threadIdx.x;
        if (i < N_NODES) cnt[i] = 0;
        return;
    }
    const int t = (blockIdx.x - ZERO_BLOCKS) * 256 + threadIdx.x;  // 0..8191
    const int kt = t >> 10;
    const int nt = (t >> 6) & 15;
    const int lane = t & 63;
    const int kbase = kt * 32 + ((lane >> 4) * 8);
    const int n = nt * 16 + (lane & 15);
    u16 frag[8];
    #pragma unroll
    for (int j = 0; j < 8; ++j)
        frag[j] = f2bf(W[(size_t)(kbase + j) * D + n]);
    #pragma unroll
    for (int j = 0; j < 8; ++j)
        Wf[(size_t)t * 8 + j] = frag[j];
}

// -------- fused: GEMM (blocks < GEMM_BLOCKS) + histogram (rest) ------------
// GEMM: one wave per 32-row tile, 2 row-halves x 16 col-tiles of 16x16x32.
__global__ __launch_bounds__(256) void gemm_hist_kernel(
    const float* __restrict__ X, const u16* __restrict__ Wf,
    u16* __restrict__ S, const int* __restrict__ row, int* __restrict__ cnt)
{
    if (blockIdx.x >= GEMM_BLOCKS) {
        const int e = (blockIdx.x - GEMM_BLOCKS) * 256 + threadIdx.x;
        atomicAdd(&cnt[row[e]], 1);
        return;
    }
    const int lane = threadIdx.x & 63;
    const int tile = blockIdx.x * 4 + (threadIdx.x >> 6);
    if (tile >= GEMM_TILES) return;
    const int row0 = tile * 32;
    const int m = lane & 15;
    const int quad = lane >> 4;

    f32x4 acc0[16], acc1[16];
    #pragma unroll
    for (int t = 0; t < 16; ++t) {
        acc0[t] = (f32x4){0.f, 0.f, 0.f, 0.f};
        acc1[t] = (f32x4){0.f, 0.f, 0.f, 0.f};
    }

    const float* xA = X + (size_t)(row0 + m) * D + quad * 8;
    const float* xB = X + (size_t)(row0 + 16 + m) * D + quad * 8;
    const bf16x8* __restrict__ Bf = (const bf16x8*)Wf;

    for (int k0 = 0; k0 < 8; ++k0) {               // K-step = 32
        const float4 a0l = *(const float4*)(xA + k0 * 32);
        const float4 a0h = *(const float4*)(xA + k0 * 32 + 4);
        const float4 a1l = *(const float4*)(xB + k0 * 32);
        const float4 a1h = *(const float4*)(xB + k0 * 32 + 4);
        bf16x8 a0, a1;
        a0[0] = (short)f2bf(a0l.x); a0[1] = (short)f2bf(a0l.y);
        a0[2] = (short)f2bf(a0l.z); a0[3] = (short)f2bf(a0l.w);
        a0[4] = (short)f2bf(a0h.x); a0[5] = (short)f2bf(a0h.y);
        a0[6] = (short)f2bf(a0h.z); a0[7] = (short)f2bf(a0h.w);
        a1[0] = (short)f2bf(a1l.x); a1[1] = (short)f2bf(a1l.y);
        a1[2] = (short)f2bf(a1l.z); a1[3] = (short)f2bf(a1l.w);
        a1[4] = (short)f2bf(a1h.x); a1[5] = (short)f2bf(a1h.y);
        a1[6] = (short)f2bf(a1h.z); a1[7] = (short)f2bf(a1h.w);

        const bf16x8* bp = Bf + (size_t)k0 * 1024 + lane;
        #pragma unroll
        for (int g = 0; g < 4; ++g) {              // 4 col-tiles per group
            const bf16x8 b0 = bp[g * 256 + 0];
            const bf16x8 b1 = bp[g * 256 + 64];
            const bf16x8 b2 = bp[g * 256 + 128];
            const bf16x8 b3 = bp[g * 256 + 192];
            acc0[g*4+0] = __builtin_amdgcn_mfma_f32_16x16x32_bf16(a0, b0, acc0[g*4+0], 0, 0, 0);
            acc1[g*4+0] = __builtin_amdgcn_mfma_f32_16x16x32_bf16(a1, b0, acc1[g*4+0], 0, 0, 0);
            acc0[g*4+1] = __builtin_amdgcn_mfma_f32_16x16x32_bf16(a0, b1, acc0[g*4+1], 0, 0, 0);
            acc1[g*4+1] = __builtin_amdgcn_mfma_f32_16x16x32_bf16(a1, b1, acc1[g*4+1], 0, 0, 0);
            acc0[g*4+2] = __builtin_amdgcn_mfma_f32_16x16x32_bf16(a0, b2, acc0[g*4+2], 0, 0, 0);
            acc1[g*4+2] = __builtin_amdgcn_mfma_f32_16x16x32_bf16(a1, b2, acc1[g*4+2], 0, 0, 0);
            acc0[g*4+3] = __builtin_amdgcn_mfma_f32_16x16x32_bf16(a0, b3, acc0[g*4+3], 0, 0, 0);
            acc1[g*4+3] = __builtin_amdgcn_mfma_f32_16x16x32_bf16(a1, b3, acc1[g*4+3], 0, 0, 0);
        }
    }

    // C/D: col = nt*16 + m, row = quad*4 + i  (+16 for second half)
    #pragma unroll
    for (int nt = 0; nt < 16; ++nt) {
        #pragma unroll
        for (int i = 0; i < 4; ++i) {
            S[(size_t)(row0 + quad * 4 + i) * D + nt * 16 + m]      = f2bf(acc0[nt][i]);
            S[(size_t)(row0 + 16 + quad * 4 + i) * D + nt * 16 + m] = f2bf(acc1[nt][i]);
        }
    }
}

// -------- hierarchical scan ------------------------------------------------
__global__ __launch_bounds__(256) void blocksum_kernel(
    const int* __restrict__ cnt, int* __restrict__ bsum)
{
    __shared__ int sh[4];
    const int i = blockIdx.x * 256 + threadIdx.x;
    int x = (i < N_NODES) ? cnt[i] : 0;
    #pragma unroll
    for (int off = 32; off > 0; off >>= 1) x += __shfl_xor(x, off);
    if ((threadIdx.x & 63) == 0) sh[threadIdx.x >> 6] = x;
    __syncthreads();
    if (threadIdx.x == 0) bsum[blockIdx.x] = sh[0] + sh[1] + sh[2] + sh[3];
}

__global__ __launch_bounds__(512) void bscan_kernel(
    const int* __restrict__ bsum, int* __restrict__ boff, int* __restrict__ starts)
{
    __shared__ int wsum[8];
    const int tid = threadIdx.x, lane = tid & 63, wv = tid >> 6;
    const int c = (tid < NBLK) ? bsum[tid] : 0;
    int x = c;
    #pragma unroll
    for (int off = 1; off < 64; off <<= 1) {
        int y = __shfl_up(x, off);
        if (lane >= off) x += y;
    }
    if (lane == 63) wsum[wv] = x;
    __syncthreads();
    if (tid == 0) {
        int run = 0;
        #pragma unroll
        for (int w = 0; w < 8; ++w) { int t = wsum[w]; wsum[w] = run; run += t; }
        starts[N_NODES] = N_EDGES;
    }
    __syncthreads();
    if (tid < NBLK) boff[tid] = x - c + wsum[wv];
}

// localscan: writes starts[] AND initializes per-bucket cursors bcur[] (the
// bucket's region in pce is [starts[b*RPB], starts[(b+1)*RPB)) by construction)
__global__ __launch_bounds__(256) void localscan_kernel(
    const int* __restrict__ cnt, const int* __restrict__ boff,
    int* __restrict__ starts, int* __restrict__ bcur)
{
    __shared__ int wsum[4];
    const int tid = threadIdx.x, lane = tid & 63, wv = tid >> 6;
    const int i = blockIdx.x * 256 + tid;
    const int c = (i < N_NODES) ? cnt[i] : 0;
    int x = c;
    #pragma unroll
    for (int off = 1; off < 64; off <<= 1) {
        int y = __shfl_up(x, off);
        if (lane >= off) x += y;
    }
    if (lane == 63) wsum[wv] = x;
    __syncthreads();
    if (tid == 0) {
        int run = 0;
        #pragma unroll
        for (int w = 0; w < 4; ++w) { int t = wsum[w]; wsum[w] = run; run += t; }
    }
    __syncthreads();
    const int excl = x - c + wsum[wv] + boff[blockIdx.x];
    if (i < N_NODES) {
        starts[i] = excl;
        if ((i & (RPB - 1)) == 0) bcur[i / RPB] = excl;
    }
}

// -------- placement pass 1: bucket-granular scatter ------------------------
// Frontier = 6250 bucket tails (~400 KB of open lines) -> L2-resident, so
// lines fill before eviction (vs 100K row tails = 6.4 MB > 4 MB/XCD L2,
// which caused the 7.7x write amplification of the old place_kernel).
// Row low bits packed above col (col < 2^17, RPB=16 -> 4 bits).
__global__ __launch_bounds__(256) void binplace_kernel(
    const int* __restrict__ row, const int* __restrict__ col,
    const float* __restrict__ val, int* __restrict__ bcur,
    uint2* __restrict__ pce)
{
    const int e = blockIdx.x * 256 + threadIdx.x;
    const int r = row[e];
    const u32 c = (u32)col[e];
    const float v = val[e];
    const int pos = atomicAdd(&bcur[r / RPB], 1);
    pce[pos] = make_uint2(c | ((u32)(r & (RPB - 1)) << 17),
                          __builtin_bit_cast(u32, v));
}

// -------- placement pass 2: in-place per-bucket counting sort --------------
// One block per bucket of RPB=16 rows (~512 entries avg). Stage entries in
// LDS, barrier (all in-place reads complete before any write), then write
// each entry to its exact CSR slot starts[r] + rank. Bucket ranges are
// disjoint across blocks, and each block fully rewrites its own ~4 KB
// region -> full-line writebacks, no amplification.
// P2_CAP=4096 is 8x the binomial mean (sigma~22.6): overflow impossible.
__global__ __launch_bounds__(256) void bucketsort_kernel(
    const int* __restrict__ starts, uint2* __restrict__ pce)
{
    __shared__ uint2 ent[P2_CAP];
    __shared__ int rbase[RPB + 1];
    __shared__ int rcnt[RPB];
    const int b = blockIdx.x;
    const int tid = threadIdx.x;
    if (tid <= RPB) rbase[tid] = starts[b * RPB + tid];
    if (tid < RPB) rcnt[tid] = 0;
    __syncthreads();
    const int base = rbase[0];
    const int n = rbase[RPB] - base;
    for (int i = tid; i < n; i += 256) ent[i] = pce[base + i];
    __syncthreads();
    for (int i = tid; i < n; i += 256) {
        const uint2 e = ent[i];
        const int rlow = (int)((e.x >> 17) & (u32)(RPB - 1));
        const int rank = atomicAdd(&rcnt[rlow], 1);
        pce[rbase[rlow] + rank] = make_uint2(e.x & 0x1FFFFu, e.y);
    }
}

// -------- segmented reduce: one wave/row, coalesced pairs, 8-deep MLP ------
__global__ __launch_bounds__(256) void reduce_kernel(
    const u16* __restrict__ S, const int* __restrict__ starts,
    const uint2* __restrict__ pce, const float* __restrict__ bias,
    float* __restrict__ out)
{
    const int lane = threadIdx.x & 63;
    const int r = blockIdx.x * 4 + (threadIdx.x >> 6);
    const int s0 = starts[r];
    const int s1 = starts[r + 1];

    const ushort4* __restrict__ S4 = (const ushort4*)S;
    float4 acc = make_float4(0.f, 0.f, 0.f, 0.f);

    for (int base = s0; base < s1; base += 64) {
        const int n = min(64, s1 - base);
        uint2 pr = make_uint2(0u, 0u);
        if (lane < n) pr = pce[base + lane];
        const int c = (int)pr.x;
        const float v = __builtin_bit_cast(float, pr.y);

        int i = 0;
        for (; i + 8 <= n; i += 8) {
            int cc[8]; float vv[8]; ushort4 s[8];
            #pragma unroll
            for (int u = 0; u < 8; ++u) {
                cc[u] = __shfl(c, i + u);
                vv[u] = __shfl(v, i + u);
            }
            #pragma unroll
            for (int u = 0; u < 8; ++u)
                s[u] = S4[(size_t)cc[u] * 64 + lane];
            #pragma unroll
            for (int u = 0; u < 8; ++u) {
                acc.x += vv[u] * bf2f(s[u].x);
                acc.y += vv[u] * bf2f(s[u].y);
                acc.z += vv[u] * bf2f(s[u].z);
                acc.w += vv[u] * bf2f(s[u].w);
            }
        }
        for (; i < n; ++i) {
            const int c0 = __shfl(c, i);
            const float v0 = __shfl(v, i);
            const ushort4 a0 = S4[(size_t)c0 * 64 + lane];
            acc.x += v0 * bf2f(a0.x);
            acc.y += v0 * bf2f(a0.y);
            acc.z += v0 * bf2f(a0.z);
            acc.w += v0 * bf2f(a0.w);
        }
    }

    const float4 b4 = ((const float4*)bias)[lane];
    acc.x += b4.x; acc.y += b4.y; acc.z += b4.z; acc.w += b4.w;
    ((float4*)out)[(size_t)r * 64 + lane] = acc;
}

extern "C" void kernel_launch(void* const* d_in, const int* in_sizes, int n_in,
                              void* d_out, int out_size, void* d_ws, size_t ws_size,
                              hipStream_t stream) {
    const float* X    = (const float*)d_in[0];
    const int*   row  = (const int*)d_in[1];
    const int*   col  = (const int*)d_in[2];
    const float* val  = (const float*)d_in[3];
    const float* W    = (const float*)d_in[4];
    const float* bias = (const float*)d_in[5];
    float* out = (float*)d_out;

    // workspace layout (~77.4 MB; cnt overlays pce base — dead before
    // binplace overwrites it; in-place bucketsort removed pce_tmp)
    char* ws = (char*)d_ws;
    u16*   Sx     = (u16*)ws;                       // 51,200,000 B
    int*   starts = (int*)(ws + 51200000);          //    400,064 B (N+1, padded)
    uint2* pce    = (uint2*)(ws + 51600064);        // 25,600,000 B (8-aligned)
    int*   cnt    = (int*)(ws + 51600064);          // overlay on pce
    u16*   Wf     = (u16*)(ws + 77200064);          //    131,072 B (16-aligned)
    int*   bsum   = (int*)(ws + 77331136);          //      2,048 B
    int*   boff   = (int*)(ws + 77333184);          //      2,048 B
    int*   bcur   = (int*)(ws + 77335232);          //     25,000 B

    // 1) prep: zero cnt + W -> bf16 B-fragment layout
    prep_kernel<<<ZERO_BLOCKS + WSH_BLOCKS, 256, 0, stream>>>(W, Wf, cnt);

    // 2) fused GEMM + histogram
    gemm_hist_kernel<<<GEMM_BLOCKS + HIST_BLOCKS, 256, 0, stream>>>(X, Wf, Sx, row, cnt);

    // 3) scan (also seeds bucket cursors)
    blocksum_kernel<<<NBLK, 256, 0, stream>>>(cnt, bsum);
    bscan_kernel<<<1, 512, 0, stream>>>(bsum, boff, starts);
    localscan_kernel<<<NBLK, 256, 0, stream>>>(cnt, boff, starts, bcur);

    // 4) placement: bucket scatter, then in-place per-bucket counting sort
    binplace_kernel<<<N_EDGES / 256, 256, 0, stream>>>(row, col, val, bcur, pce);
    bucketsort_kernel<<<NB_BUCKETS, 256, 0, stream>>>(starts, pce);

    // 5) segmented reduce
    reduce_kernel<<<N_NODES / 4, 256, 0, stream>>>(Sx, starts, pce, bias, out);
}

// Round 2
// 717.697 us; speedup vs baseline: 1.1204x; 1.0083x over previous
//
#include <hip/hip_runtime.h>

#define N_NODES 100000
#define N_EDGES 3200000
#define D 256
#define NBLK ((N_NODES + 255) / 256)     // 391 scan blocks
#define GEMM_TILES (N_NODES / 32)        // 3125 tiles of 32 rows
#define GEMM_BLOCKS ((GEMM_TILES + 3) / 4)  // 782
#define HIST_BLOCKS (N_EDGES / 256)      // 12500
#define ZERO_BLOCKS NBLK                 // 391
#define WSH_BLOCKS 32

#define RPB 16                           // rows per bucket
#define NB_BUCKETS (N_NODES / RPB)       // 6250 (exact)
#define P2_CAP 4096                      // LDS entry cap (mean 512, 30+ sigma)

using u16 = unsigned short;
using u32 = unsigned int;

typedef __attribute__((ext_vector_type(8))) short bf16x8;
typedef __attribute__((ext_vector_type(4))) float f32x4;

__device__ inline u16 f2bf(float f) {
    u32 x = __builtin_bit_cast(u32, f);
    return (u16)((x + 0x7FFFu + ((x >> 16) & 1u)) >> 16);
}
__device__ inline float bf2f(u16 u) {
    return __builtin_bit_cast(float, (u32)u << 16);
}

// -------- prep: zero cnt (blocks 0..390) + W shuffle (blocks 391..422) -----
// Wf layout [kt(8)][nt(16)][lane(64)][j(8)]:
//   b[j] = W[kt*32 + (lane>>4)*8 + j][nt*16 + (lane&15)]
__global__ __launch_bounds__(256) void prep_kernel(
    const float* __restrict__ W, u16* __restrict__ Wf, int* __restrict__ cnt)
{
    if (blockIdx.x < ZERO_BLOCKS) {
        const int i = blockIdx.x * 256 + threadIdx.x;
        if (i < N_NODES) cnt[i] = 0;
        return;
    }
    const int t = (blockIdx.x - ZERO_BLOCKS) * 256 + threadIdx.x;  // 0..8191
    const int kt = t >> 10;
    const int nt = (t >> 6) & 15;
    const int lane = t & 63;
    const int kbase = kt * 32 + ((lane >> 4) * 8);
    const int n = nt * 16 + (lane & 15);
    u16 frag[8];
    #pragma unroll
    for (int j = 0; j < 8; ++j)
        frag[j] = f2bf(W[(size_t)(kbase + j) * D + n]);
    #pragma unroll
    for (int j = 0; j < 8; ++j)
        Wf[(size_t)t * 8 + j] = frag[j];
}

// -------- fused: GEMM (blocks < GEMM_BLOCKS) + histogram (rest) ------------
// GEMM: one wave per 32-row tile, 2 row-halves x 16 col-tiles of 16x16x32.
// S is stored as TWO COLUMN PLANES: S[plane][row][128] bf16 (25.6 MB each) so
// the segmented reduce can process one L2-resident plane at a time.
__global__ __launch_bounds__(256) void gemm_hist_kernel(
    const float* __restrict__ X, const u16* __restrict__ Wf,
    u16* __restrict__ S, const int* __restrict__ row, int* __restrict__ cnt)
{
    if (blockIdx.x >= GEMM_BLOCKS) {
        const int e = (blockIdx.x - GEMM_BLOCKS) * 256 + threadIdx.x;
        atomicAdd(&cnt[row[e]], 1);
        return;
    }
    const int lane = threadIdx.x & 63;
    const int tile = blockIdx.x * 4 + (threadIdx.x >> 6);
    if (tile >= GEMM_TILES) return;
    const int row0 = tile * 32;
    const int m = lane & 15;
    const int quad = lane >> 4;

    f32x4 acc0[16], acc1[16];
    #pragma unroll
    for (int t = 0; t < 16; ++t) {
        acc0[t] = (f32x4){0.f, 0.f, 0.f, 0.f};
        acc1[t] = (f32x4){0.f, 0.f, 0.f, 0.f};
    }

    const float* xA = X + (size_t)(row0 + m) * D + quad * 8;
    const float* xB = X + (size_t)(row0 + 16 + m) * D + quad * 8;
    const bf16x8* __restrict__ Bf = (const bf16x8*)Wf;

    for (int k0 = 0; k0 < 8; ++k0) {               // K-step = 32
        const float4 a0l = *(const float4*)(xA + k0 * 32);
        const float4 a0h = *(const float4*)(xA + k0 * 32 + 4);
        const float4 a1l = *(const float4*)(xB + k0 * 32);
        const float4 a1h = *(const float4*)(xB + k0 * 32 + 4);
        bf16x8 a0, a1;
        a0[0] = (short)f2bf(a0l.x); a0[1] = (short)f2bf(a0l.y);
        a0[2] = (short)f2bf(a0l.z); a0[3] = (short)f2bf(a0l.w);
        a0[4] = (short)f2bf(a0h.x); a0[5] = (short)f2bf(a0h.y);
        a0[6] = (short)f2bf(a0h.z); a0[7] = (short)f2bf(a0h.w);
        a1[0] = (short)f2bf(a1l.x); a1[1] = (short)f2bf(a1l.y);
        a1[2] = (short)f2bf(a1l.z); a1[3] = (short)f2bf(a1l.w);
        a1[4] = (short)f2bf(a1h.x); a1[5] = (short)f2bf(a1h.y);
        a1[6] = (short)f2bf(a1h.z); a1[7] = (short)f2bf(a1h.w);

        const bf16x8* bp = Bf + (size_t)k0 * 1024 + lane;
        #pragma unroll
        for (int g = 0; g < 4; ++g) {              // 4 col-tiles per group
            const bf16x8 b0 = bp[g * 256 + 0];
            const bf16x8 b1 = bp[g * 256 + 64];
            const bf16x8 b2 = bp[g * 256 + 128];
            const bf16x8 b3 = bp[g * 256 + 192];
            acc0[g*4+0] = __builtin_amdgcn_mfma_f32_16x16x32_bf16(a0, b0, acc0[g*4+0], 0, 0, 0);
            acc1[g*4+0] = __builtin_amdgcn_mfma_f32_16x16x32_bf16(a1, b0, acc1[g*4+0], 0, 0, 0);
            acc0[g*4+1] = __builtin_amdgcn_mfma_f32_16x16x32_bf16(a0, b1, acc0[g*4+1], 0, 0, 0);
            acc1[g*4+1] = __builtin_amdgcn_mfma_f32_16x16x32_bf16(a1, b1, acc1[g*4+1], 0, 0, 0);
            acc0[g*4+2] = __builtin_amdgcn_mfma_f32_16x16x32_bf16(a0, b2, acc0[g*4+2], 0, 0, 0);
            acc1[g*4+2] = __builtin_amdgcn_mfma_f32_16x16x32_bf16(a1, b2, acc1[g*4+2], 0, 0, 0);
            acc0[g*4+3] = __builtin_amdgcn_mfma_f32_16x16x32_bf16(a0, b3, acc0[g*4+3], 0, 0, 0);
            acc1[g*4+3] = __builtin_amdgcn_mfma_f32_16x16x32_bf16(a1, b3, acc1[g*4+3], 0, 0, 0);
        }
    }

    // C/D: col = nt*16 + m, row = quad*4 + i  (+16 for second half)
    // plane = nt>>3, in-plane col = (nt&7)*16 + m, plane row stride = 128
    #pragma unroll
    for (int nt = 0; nt < 16; ++nt) {
        u16* Sp = S + (size_t)(nt >> 3) * ((size_t)N_NODES * 128);
        const int cip = (nt & 7) * 16 + m;
        #pragma unroll
        for (int i = 0; i < 4; ++i) {
            Sp[(size_t)(row0 + quad * 4 + i) * 128 + cip]      = f2bf(acc0[nt][i]);
            Sp[(size_t)(row0 + 16 + quad * 4 + i) * 128 + cip] = f2bf(acc1[nt][i]);
        }
    }
}

// -------- hierarchical scan ------------------------------------------------
__global__ __launch_bounds__(256) void blocksum_kernel(
    const int* __restrict__ cnt, int* __restrict__ bsum)
{
    __shared__ int sh[4];
    const int i = blockIdx.x * 256 + threadIdx.x;
    int x = (i < N_NODES) ? cnt[i] : 0;
    #pragma unroll
    for (int off = 32; off > 0; off >>= 1) x += __shfl_xor(x, off);
    if ((threadIdx.x & 63) == 0) sh[threadIdx.x >> 6] = x;
    __syncthreads();
    if (threadIdx.x == 0) bsum[blockIdx.x] = sh[0] + sh[1] + sh[2] + sh[3];
}

__global__ __launch_bounds__(512) void bscan_kernel(
    const int* __restrict__ bsum, int* __restrict__ boff, int* __restrict__ starts)
{
    __shared__ int wsum[8];
    const int tid = threadIdx.x, lane = tid & 63, wv = tid >> 6;
    const int c = (tid < NBLK) ? bsum[tid] : 0;
    int x = c;
    #pragma unroll
    for (int off = 1; off < 64; off <<= 1) {
        int y = __shfl_up(x, off);
        if (lane >= off) x += y;
    }
    if (lane == 63) wsum[wv] = x;
    __syncthreads();
    if (tid == 0) {
        int run = 0;
        #pragma unroll
        for (int w = 0; w < 8; ++w) { int t = wsum[w]; wsum[w] = run; run += t; }
        starts[N_NODES] = N_EDGES;
    }
    __syncthreads();
    if (tid < NBLK) boff[tid] = x - c + wsum[wv];
}

// localscan: writes starts[] AND initializes per-bucket cursors bcur[] (the
// bucket's region in pce is [starts[b*RPB], starts[(b+1)*RPB)) by construction)
__global__ __launch_bounds__(256) void localscan_kernel(
    const int* __restrict__ cnt, const int* __restrict__ boff,
    int* __restrict__ starts, int* __restrict__ bcur)
{
    __shared__ int wsum[4];
    const int tid = threadIdx.x, lane = tid & 63, wv = tid >> 6;
    const int i = blockIdx.x * 256 + tid;
    const int c = (i < N_NODES) ? cnt[i] : 0;
    int x = c;
    #pragma unroll
    for (int off = 1; off < 64; off <<= 1) {
        int y = __shfl_up(x, off);
        if (lane >= off) x += y;
    }
    if (lane == 63) wsum[wv] = x;
    __syncthreads();
    if (tid == 0) {
        int run = 0;
        #pragma unroll
        for (int w = 0; w < 4; ++w) { int t = wsum[w]; wsum[w] = run; run += t; }
    }
    __syncthreads();
    const int excl = x - c + wsum[wv] + boff[blockIdx.x];
    if (i < N_NODES) {
        starts[i] = excl;
        if ((i & (RPB - 1)) == 0) bcur[i / RPB] = excl;
    }
}

// -------- placement pass 1: bucket-granular scatter ------------------------
// Frontier = 6250 bucket tails (~400 KB of open lines) -> L2-resident.
// Row low bits packed above col (col < 2^17, RPB=16 -> 4 bits).
__global__ __launch_bounds__(256) void binplace_kernel(
    const int* __restrict__ row, const int* __restrict__ col,
    const float* __restrict__ val, int* __restrict__ bcur,
    uint2* __restrict__ pce)
{
    const int e = blockIdx.x * 256 + threadIdx.x;
    const int r = row[e];
    const u32 c = (u32)col[e];
    const float v = val[e];
    const int pos = atomicAdd(&bcur[r / RPB], 1);
    pce[pos] = make_uint2(c | ((u32)(r & (RPB - 1)) << 17),
                          __builtin_bit_cast(u32, v));
}

// -------- placement pass 2: in-place per-bucket counting sort --------------
__global__ __launch_bounds__(256) void bucketsort_kernel(
    const int* __restrict__ starts, uint2* __restrict__ pce)
{
    __shared__ uint2 ent[P2_CAP];
    __shared__ int rbase[RPB + 1];
    __shared__ int rcnt[RPB];
    const int b = blockIdx.x;
    const int tid = threadIdx.x;
    if (tid <= RPB) rbase[tid] = starts[b * RPB + tid];
    if (tid < RPB) rcnt[tid] = 0;
    __syncthreads();
    const int base = rbase[0];
    const int n = rbase[RPB] - base;
    for (int i = tid; i < n; i += 256) ent[i] = pce[base + i];
    __syncthreads();
    for (int i = tid; i < n; i += 256) {
        const uint2 e = ent[i];
        const int rlow = (int)((e.x >> 17) & (u32)(RPB - 1));
        const int rank = atomicAdd(&rcnt[rlow], 1);
        pce[rbase[rlow] + rank] = make_uint2(e.x & 0x1FFFFu, e.y);
    }
}

// -------- segmented reduce: one wave/row, ONE COLUMN PLANE per launch ------
// Plane working set = 25.6 MB (vs 51.2) -> fits the ~28-32 MB effective L2
// capacity the round-1 counters implied (55% hit at 51.2 MB ws). Each lane
// covers 2 cols (u32 load = 256 B/wave per gathered row, fully coalesced).
__global__ __launch_bounds__(256) void reduce_kernel(
    const u16* __restrict__ S, const int* __restrict__ starts,
    const uint2* __restrict__ pce, const float* __restrict__ bias,
    float* __restrict__ out, int plane)
{
    const int lane = threadIdx.x & 63;
    const int r = blockIdx.x * 4 + (threadIdx.x >> 6);
    const int s0 = starts[r];
    const int s1 = starts[r + 1];

    const u32* __restrict__ Sp =
        (const u32*)(S + (size_t)plane * ((size_t)N_NODES * 128));
    float2 acc = make_float2(0.f, 0.f);

    for (int base = s0; base < s1; base += 64) {
        const int n = min(64, s1 - base);
        uint2 pr = make_uint2(0u, 0u);
        if (lane < n) pr = pce[base + lane];
        const int c = (int)pr.x;
        const float v = __builtin_bit_cast(float, pr.y);

        int i = 0;
        for (; i + 8 <= n; i += 8) {
            int cc[8]; float vv[8]; u32 s[8];
            #pragma unroll
            for (int u = 0; u < 8; ++u) {
                cc[u] = __shfl(c, i + u);
                vv[u] = __shfl(v, i + u);
            }
            #pragma unroll
            for (int u = 0; u < 8; ++u)
                s[u] = Sp[(size_t)cc[u] * 64 + lane];
            #pragma unroll
            for (int u = 0; u < 8; ++u) {
                acc.x += vv[u] * bf2f((u16)(s[u] & 0xFFFFu));
                acc.y += vv[u] * bf2f((u16)(s[u] >> 16));
            }
        }
        for (; i < n; ++i) {
            const int c0 = __shfl(c, i);
            const float v0 = __shfl(v, i);
            const u32 a0 = Sp[(size_t)c0 * 64 + lane];
            acc.x += v0 * bf2f((u16)(a0 & 0xFFFFu));
            acc.y += v0 * bf2f((u16)(a0 >> 16));
        }
    }

    const float2 b2 = ((const float2*)bias)[plane * 64 + lane];
    acc.x += b2.x; acc.y += b2.y;
    ((float2*)out)[(size_t)r * 128 + plane * 64 + lane] = acc;
}

extern "C" void kernel_launch(void* const* d_in, const int* in_sizes, int n_in,
                              void* d_out, int out_size, void* d_ws, size_t ws_size,
                              hipStream_t stream) {
    const float* X    = (const float*)d_in[0];
    const int*   row  = (const int*)d_in[1];
    const int*   col  = (const int*)d_in[2];
    const float* val  = (const float*)d_in[3];
    const float* W    = (const float*)d_in[4];
    const float* bias = (const float*)d_in[5];
    float* out = (float*)d_out;

    // workspace layout (~77.4 MB; cnt overlays pce base — dead before
    // binplace overwrites it)
    char* ws = (char*)d_ws;
    u16*   Sx     = (u16*)ws;                       // 51,200,000 B (2 planes)
    int*   starts = (int*)(ws + 51200000);          //    400,064 B (N+1, padded)
    uint2* pce    = (uint2*)(ws + 51600064);        // 25,600,000 B (8-aligned)
    int*   cnt    = (int*)(ws + 51600064);          // overlay on pce
    u16*   Wf     = (u16*)(ws + 77200064);          //    131,072 B (16-aligned)
    int*   bsum   = (int*)(ws + 77331136);          //      2,048 B
    int*   boff   = (int*)(ws + 77333184);          //      2,048 B
    int*   bcur   = (int*)(ws + 77335232);          //     25,000 B

    // 1) prep: zero cnt + W -> bf16 B-fragment layout
    prep_kernel<<<ZERO_BLOCKS + WSH_BLOCKS, 256, 0, stream>>>(W, Wf, cnt);

    // 2) fused GEMM + histogram
    gemm_hist_kernel<<<GEMM_BLOCKS + HIST_BLOCKS, 256, 0, stream>>>(X, Wf, Sx, row, cnt);

    // 3) scan (also seeds bucket cursors)
    blocksum_kernel<<<NBLK, 256, 0, stream>>>(cnt, bsum);
    bscan_kernel<<<1, 512, 0, stream>>>(bsum, boff, starts);
    localscan_kernel<<<NBLK, 256, 0, stream>>>(cnt, boff, starts, bcur);

    // 4) placement: bucket scatter, then in-place per-bucket counting sort
    binplace_kernel<<<N_EDGES / 256, 256, 0, stream>>>(row, col, val, bcur, pce);
    bucketsort_kernel<<<NB_BUCKETS, 256, 0, stream>>>(starts, pce);

    // 5) segmented reduce, one 128-col plane per launch (L2-resident plane)
    reduce_kernel<<<N_NODES / 4, 256, 0, stream>>>(Sx, starts, pce, bias, out, 0);
    reduce_kernel<<<N_NODES / 4, 256, 0, stream>>>(Sx, starts, pce, bias, out, 1);
}

// Round 3
// 623.866 us; speedup vs baseline: 1.2889x; 1.1504x over previous
//
#include <hip/hip_runtime.h>

#define N_NODES 100000
#define N_EDGES 3200000
#define D 256
#define GEMM_TILES (N_NODES / 32)        // 3125 tiles of 32 rows
#define GEMM_BLOCKS ((GEMM_TILES + 3) / 4)  // 782
#define WSH_BLOCKS 32

#define RPB 16                           // rows per bucket
#define NB_BUCKETS (N_NODES / RPB)       // 6250 (exact)
#define NBLK_B ((NB_BUCKETS + 255) / 256)  // 25 bucket-scan blocks
#define P2_CAP 4096                      // LDS entry cap (mean 512, 30+ sigma)

#define HIST_P 256                       // histogram partitions
#define EDGES_PER_HB (N_EDGES / HIST_P)  // 12500

using u16 = unsigned short;
using u32 = unsigned int;

typedef __attribute__((ext_vector_type(8))) short bf16x8;
typedef __attribute__((ext_vector_type(4))) float f32x4;

__device__ inline u16 f2bf(float f) {
    u32 x = __builtin_bit_cast(u32, f);
    return (u16)((x + 0x7FFFu + ((x >> 16) & 1u)) >> 16);
}
__device__ inline float bf2f(u16 u) {
    return __builtin_bit_cast(float, (u32)u << 16);
}

// -------- prep: W -> bf16 B-fragment layout --------------------------------
// Wf layout [kt(8)][nt(16)][lane(64)][j(8)]:
//   b[j] = W[kt*32 + (lane>>4)*8 + j][nt*16 + (lane&15)]
__global__ __launch_bounds__(256) void prep_kernel(
    const float* __restrict__ W, u16* __restrict__ Wf)
{
    const int t = blockIdx.x * 256 + threadIdx.x;  // 0..8191
    const int kt = t >> 10;
    const int nt = (t >> 6) & 15;
    const int lane = t & 63;
    const int kbase = kt * 32 + ((lane >> 4) * 8);
    const int n = nt * 16 + (lane & 15);
    u16 frag[8];
    #pragma unroll
    for (int j = 0; j < 8; ++j)
        frag[j] = f2bf(W[(size_t)(kbase + j) * D + n]);
    #pragma unroll
    for (int j = 0; j < 8; ++j)
        Wf[(size_t)t * 8 + j] = frag[j];
}

// -------- GEMM (de-fused from histogram for counter attribution) -----------
// One wave per 32-row tile, 2 row-halves x 16 col-tiles of 16x16x32.
// S stored as two column planes S[plane][row][128] bf16 (25.6 MB each).
__global__ __launch_bounds__(256) void gemm_kernel(
    const float* __restrict__ X, const u16* __restrict__ Wf,
    u16* __restrict__ S)
{
    const int lane = threadIdx.x & 63;
    const int tile = blockIdx.x * 4 + (threadIdx.x >> 6);
    if (tile >= GEMM_TILES) return;
    const int row0 = tile * 32;
    const int m = lane & 15;
    const int quad = lane >> 4;

    f32x4 acc0[16], acc1[16];
    #pragma unroll
    for (int t = 0; t < 16; ++t) {
        acc0[t] = (f32x4){0.f, 0.f, 0.f, 0.f};
        acc1[t] = (f32x4){0.f, 0.f, 0.f, 0.f};
    }

    const float* xA = X + (size_t)(row0 + m) * D + quad * 8;
    const float* xB = X + (size_t)(row0 + 16 + m) * D + quad * 8;
    const bf16x8* __restrict__ Bf = (const bf16x8*)Wf;

    for (int k0 = 0; k0 < 8; ++k0) {               // K-step = 32
        const float4 a0l = *(const float4*)(xA + k0 * 32);
        const float4 a0h = *(const float4*)(xA + k0 * 32 + 4);
        const float4 a1l = *(const float4*)(xB + k0 * 32);
        const float4 a1h = *(const float4*)(xB + k0 * 32 + 4);
        bf16x8 a0, a1;
        a0[0] = (short)f2bf(a0l.x); a0[1] = (short)f2bf(a0l.y);
        a0[2] = (short)f2bf(a0l.z); a0[3] = (short)f2bf(a0l.w);
        a0[4] = (short)f2bf(a0h.x); a0[5] = (short)f2bf(a0h.y);
        a0[6] = (short)f2bf(a0h.z); a0[7] = (short)f2bf(a0h.w);
        a1[0] = (short)f2bf(a1l.x); a1[1] = (short)f2bf(a1l.y);
        a1[2] = (short)f2bf(a1l.z); a1[3] = (short)f2bf(a1l.w);
        a1[4] = (short)f2bf(a1h.x); a1[5] = (short)f2bf(a1h.y);
        a1[6] = (short)f2bf(a1h.z); a1[7] = (short)f2bf(a1h.w);

        const bf16x8* bp = Bf + (size_t)k0 * 1024 + lane;
        #pragma unroll
        for (int g = 0; g < 4; ++g) {              // 4 col-tiles per group
            const bf16x8 b0 = bp[g * 256 + 0];
            const bf16x8 b1 = bp[g * 256 + 64];
            const bf16x8 b2 = bp[g * 256 + 128];
            const bf16x8 b3 = bp[g * 256 + 192];
            acc0[g*4+0] = __builtin_amdgcn_mfma_f32_16x16x32_bf16(a0, b0, acc0[g*4+0], 0, 0, 0);
            acc1[g*4+0] = __builtin_amdgcn_mfma_f32_16x16x32_bf16(a1, b0, acc1[g*4+0], 0, 0, 0);
            acc0[g*4+1] = __builtin_amdgcn_mfma_f32_16x16x32_bf16(a0, b1, acc0[g*4+1], 0, 0, 0);
            acc1[g*4+1] = __builtin_amdgcn_mfma_f32_16x16x32_bf16(a1, b1, acc1[g*4+1], 0, 0, 0);
            acc0[g*4+2] = __builtin_amdgcn_mfma_f32_16x16x32_bf16(a0, b2, acc0[g*4+2], 0, 0, 0);
            acc1[g*4+2] = __builtin_amdgcn_mfma_f32_16x16x32_bf16(a1, b2, acc1[g*4+2], 0, 0, 0);
            acc0[g*4+3] = __builtin_amdgcn_mfma_f32_16x16x32_bf16(a0, b3, acc0[g*4+3], 0, 0, 0);
            acc1[g*4+3] = __builtin_amdgcn_mfma_f32_16x16x32_bf16(a1, b3, acc1[g*4+3], 0, 0, 0);
        }
    }

    // C/D: col = nt*16 + m, row = quad*4 + i  (+16 for second half)
    // plane = nt>>3, in-plane col = (nt&7)*16 + m, plane row stride = 128
    #pragma unroll
    for (int nt = 0; nt < 16; ++nt) {
        u16* Sp = S + (size_t)(nt >> 3) * ((size_t)N_NODES * 128);
        const int cip = (nt & 7) * 16 + m;
        #pragma unroll
        for (int i = 0; i < 4; ++i) {
            Sp[(size_t)(row0 + quad * 4 + i) * 128 + cip]      = f2bf(acc0[nt][i]);
            Sp[(size_t)(row0 + 16 + quad * 4 + i) * 128 + cip] = f2bf(acc1[nt][i]);
        }
    }
}

// -------- histogram: LDS bucket counts, plain-write flush (NO device atomics)
// 3.2M device-scope atomics onto 6250 shared cache lines were the old fused
// kernel's ~170 us (XCD line ping-pong). LDS atomics + 6.4 MB coalesced flush
// replace them entirely.
__global__ __launch_bounds__(1024) void hist_kernel(
    const int* __restrict__ row, u32* __restrict__ hglob)
{
    __shared__ u32 h[NB_BUCKETS];
    const int tid = threadIdx.x;
    for (int j = tid; j < NB_BUCKETS; j += 1024) h[j] = 0u;
    __syncthreads();
    const int e0 = blockIdx.x * EDGES_PER_HB;
    for (int i = tid; i < EDGES_PER_HB; i += 1024)
        atomicAdd(&h[row[e0 + i] >> 4], 1u);
    __syncthreads();
    u32* dst = hglob + (size_t)blockIdx.x * NB_BUCKETS;
    for (int j = tid; j < NB_BUCKETS; j += 1024) dst[j] = h[j];
}

// -------- column-sum of per-partition histograms + per-block sums ----------
__global__ __launch_bounds__(256) void colsum_kernel(
    const u32* __restrict__ hglob, u32* __restrict__ tot, int* __restrict__ bsum)
{
    __shared__ int sh[4];
    const int b = blockIdx.x * 256 + threadIdx.x;
    u32 s = 0u;
    if (b < NB_BUCKETS) {
        #pragma unroll 8
        for (int p = 0; p < HIST_P; ++p)
            s += hglob[(size_t)p * NB_BUCKETS + b];
        tot[b] = s;
    }
    int x = (int)s;
    #pragma unroll
    for (int off = 32; off > 0; off >>= 1) x += __shfl_xor(x, off);
    if ((threadIdx.x & 63) == 0) sh[threadIdx.x >> 6] = x;
    __syncthreads();
    if (threadIdx.x == 0) bsum[blockIdx.x] = sh[0] + sh[1] + sh[2] + sh[3];
}

// -------- scan of the 25 block sums (single wave) --------------------------
__global__ __launch_bounds__(64) void bscan_kernel(
    const int* __restrict__ bsum, int* __restrict__ boff,
    int* __restrict__ starts, int* __restrict__ bstart)
{
    const int tid = threadIdx.x;
    const int c = (tid < NBLK_B) ? bsum[tid] : 0;
    int x = c;
    #pragma unroll
    for (int off = 1; off < 64; off <<= 1) {
        int y = __shfl_up(x, off);
        if (tid >= off) x += y;
    }
    if (tid < NBLK_B) boff[tid] = x - c;
    if (tid == 0) {
        starts[N_NODES] = N_EDGES;
        bstart[NB_BUCKETS] = N_EDGES;
    }
}

// -------- bucket-level local scan: bstart[] and bcur[] ---------------------
__global__ __launch_bounds__(256) void blocalscan_kernel(
    const u32* __restrict__ tot, const int* __restrict__ boff,
    int* __restrict__ bstart, int* __restrict__ bcur)
{
    __shared__ int wsum[4];
    const int tid = threadIdx.x, lane = tid & 63, wv = tid >> 6;
    const int i = blockIdx.x * 256 + tid;
    const int c = (i < NB_BUCKETS) ? (int)tot[i] : 0;
    int x = c;
    #pragma unroll
    for (int off = 1; off < 64; off <<= 1) {
        int y = __shfl_up(x, off);
        if (lane >= off) x += y;
    }
    if (lane == 63) wsum[wv] = x;
    __syncthreads();
    if (tid == 0) {
        int run = 0;
        #pragma unroll
        for (int w = 0; w < 4; ++w) { int t = wsum[w]; wsum[w] = run; run += t; }
    }
    __syncthreads();
    const int excl = x - c + wsum[wv] + boff[blockIdx.x];
    if (i < NB_BUCKETS) { bstart[i] = excl; bcur[i] = excl; }
}

// -------- placement pass 1: bucket-granular scatter ------------------------
// Frontier = 6250 bucket tails (~400 KB of open lines) -> L2-resident.
// Row low bits packed above col (col < 2^17, RPB=16 -> 4 bits).
__global__ __launch_bounds__(256) void binplace_kernel(
    const int* __restrict__ row, const int* __restrict__ col,
    const float* __restrict__ val, int* __restrict__ bcur,
    uint2* __restrict__ pce)
{
    const int e = blockIdx.x * 256 + threadIdx.x;
    const int r = row[e];
    const u32 c = (u32)col[e];
    const float v = val[e];
    const int pos = atomicAdd(&bcur[r / RPB], 1);
    pce[pos] = make_uint2(c | ((u32)(r & (RPB - 1)) << 17),
                          __builtin_bit_cast(u32, v));
}

// -------- placement pass 2: in-place counting sort + per-row starts --------
// Computes the per-row CSR starts itself (count -> prefix -> write), which
// replaced the 100K-row global scan chain.
__global__ __launch_bounds__(256) void bucketsort_kernel(
    const int* __restrict__ bstart, uint2* __restrict__ pce,
    int* __restrict__ starts)
{
    __shared__ uint2 ent[P2_CAP];
    __shared__ int rcnt[RPB];
    __shared__ int rcur[RPB];
    const int b = blockIdx.x;
    const int tid = threadIdx.x;
    const int base = bstart[b];
    const int n = bstart[b + 1] - base;
    if (tid < RPB) rcnt[tid] = 0;
    __syncthreads();
    for (int i = tid; i < n; i += 256) ent[i] = pce[base + i];
    __syncthreads();
    for (int i = tid; i < n; i += 256)
        atomicAdd(&rcnt[(ent[i].x >> 17) & (RPB - 1)], 1);
    __syncthreads();
    if (tid == 0) {
        int run = 0;
        #pragma unroll
        for (int j = 0; j < RPB; ++j) { rcur[j] = run; run += rcnt[j]; }
    }
    __syncthreads();
    if (tid < RPB) starts[b * RPB + tid] = base + rcur[tid];
    __syncthreads();
    for (int i = tid; i < n; i += 256) {
        const uint2 e = ent[i];
        const int rl = (int)((e.x >> 17) & (u32)(RPB - 1));
        const int pos = atomicAdd(&rcur[rl], 1);
        pce[base + pos] = make_uint2(e.x & 0x1FFFFu, e.y);
    }
}

// -------- segmented reduce: one wave/row, ONE COLUMN PLANE per launch ------
__global__ __launch_bounds__(256) void reduce_kernel(
    const u16* __restrict__ S, const int* __restrict__ starts,
    const uint2* __restrict__ pce, const float* __restrict__ bias,
    float* __restrict__ out, int plane)
{
    const int lane = threadIdx.x & 63;
    const int r = blockIdx.x * 4 + (threadIdx.x >> 6);
    const int s0 = starts[r];
    const int s1 = starts[r + 1];

    const u32* __restrict__ Sp =
        (const u32*)(S + (size_t)plane * ((size_t)N_NODES * 128));
    float2 acc = make_float2(0.f, 0.f);

    for (int base = s0; base < s1; base += 64) {
        const int n = min(64, s1 - base);
        uint2 pr = make_uint2(0u, 0u);
        if (lane < n) pr = pce[base + lane];
        const int c = (int)pr.x;
        const float v = __builtin_bit_cast(float, pr.y);

        int i = 0;
        for (; i + 8 <= n; i += 8) {
            int cc[8]; float vv[8]; u32 s[8];
            #pragma unroll
            for (int u = 0; u < 8; ++u) {
                cc[u] = __shfl(c, i + u);
                vv[u] = __shfl(v, i + u);
            }
            #pragma unroll
            for (int u = 0; u < 8; ++u)
                s[u] = Sp[(size_t)cc[u] * 64 + lane];
            #pragma unroll
            for (int u = 0; u < 8; ++u) {
                acc.x += vv[u] * bf2f((u16)(s[u] & 0xFFFFu));
                acc.y += vv[u] * bf2f((u16)(s[u] >> 16));
            }
        }
        for (; i < n; ++i) {
            const int c0 = __shfl(c, i);
            const float v0 = __shfl(v, i);
            const u32 a0 = Sp[(size_t)c0 * 64 + lane];
            acc.x += v0 * bf2f((u16)(a0 & 0xFFFFu));
            acc.y += v0 * bf2f((u16)(a0 >> 16));
        }
    }

    const float2 b2 = ((const float2*)bias)[plane * 64 + lane];
    acc.x += b2.x; acc.y += b2.y;
    ((float2*)out)[(size_t)r * 128 + plane * 64 + lane] = acc;
}

extern "C" void kernel_launch(void* const* d_in, const int* in_sizes, int n_in,
                              void* d_out, int out_size, void* d_ws, size_t ws_size,
                              hipStream_t stream) {
    const float* X    = (const float*)d_in[0];
    const int*   row  = (const int*)d_in[1];
    const int*   col  = (const int*)d_in[2];
    const float* val  = (const float*)d_in[3];
    const float* W    = (const float*)d_in[4];
    const float* bias = (const float*)d_in[5];
    float* out = (float*)d_out;

    // workspace layout (~83.8 MB; >=102.4 MB proven available)
    char* ws = (char*)d_ws;
    u16*   Sx     = (u16*)ws;                       // 51,200,000 B (2 planes)
    int*   starts = (int*)(ws + 51200000);          //    400,064 B (N+1, padded)
    uint2* pce    = (uint2*)(ws + 51600064);        // 25,600,000 B (8-aligned)
    u16*   Wf     = (u16*)(ws + 77200064);          //    131,072 B (16-aligned)
    u32*   hglob  = (u32*)(ws + 77331136);          //  6,400,000 B (256x6250)
    u32*   tot    = (u32*)(ws + 83731136);          //     25,600 B
    int*   bsum   = (int*)(ws + 83756736);          //      1,024 B
    int*   boff   = (int*)(ws + 83757760);          //      1,024 B
    int*   bstart = (int*)(ws + 83758784);          //     25,600 B (6251)
    int*   bcur   = (int*)(ws + 83784384);          //     25,600 B

    // 1) prep: W -> bf16 B-fragment layout
    prep_kernel<<<WSH_BLOCKS, 256, 0, stream>>>(W, Wf);

    // 2) GEMM (de-fused for attribution)
    gemm_kernel<<<GEMM_BLOCKS, 256, 0, stream>>>(X, Wf, Sx);

    // 3) atomic-free bucket histogram + tiny scan chain
    hist_kernel<<<HIST_P, 1024, 0, stream>>>(row, hglob);
    colsum_kernel<<<NBLK_B, 256, 0, stream>>>(hglob, tot, bsum);
    bscan_kernel<<<1, 64, 0, stream>>>(bsum, boff, starts, bstart);
    blocalscan_kernel<<<NBLK_B, 256, 0, stream>>>(tot, boff, bstart, bcur);

    // 4) placement: bucket scatter, then in-place counting sort (+starts)
    binplace_kernel<<<N_EDGES / 256, 256, 0, stream>>>(row, col, val, bcur, pce);
    bucketsort_kernel<<<NB_BUCKETS, 256, 0, stream>>>(bstart, pce, starts);

    // 5) segmented reduce, one 128-col plane per launch (L2-resident plane)
    reduce_kernel<<<N_NODES / 4, 256, 0, stream>>>(Sx, starts, pce, bias, out, 0);
    reduce_kernel<<<N_NODES / 4, 256, 0, stream>>>(Sx, starts, pce, bias, out, 1);
}

// Round 4
// 588.136 us; speedup vs baseline: 1.3672x; 1.0608x over previous
//
#include <hip/hip_runtime.h>

#define N_NODES 100000
#define N_EDGES 3200000
#define D 256
#define GEMM_TILES (N_NODES / 32)        // 3125 tiles of 32 rows
#define GEMM_BLOCKS ((GEMM_TILES + 3) / 4)  // 782
#define WSH_BLOCKS 32

#define BIN_SHIFT 6                      // 64 rows per bin
#define BIN_ROWS 64
#define NBIN 1563                        // ceil(100000/64)
#define P1 128                           // scatter partitions
#define EPP (N_EDGES / P1)               // 25000 edges per partition
#define BSORT_CAP 4096                   // LDS entries/bin (mean 2048, 45 sigma)

using u16 = unsigned short;
using u32 = unsigned int;

typedef __attribute__((ext_vector_type(8))) short bf16x8;
typedef __attribute__((ext_vector_type(4))) float f32x4;

__device__ inline u16 f2bf(float f) {
    u32 x = __builtin_bit_cast(u32, f);
    return (u16)((x + 0x7FFFu + ((x >> 16) & 1u)) >> 16);
}
__device__ inline float bf2f(u16 u) {
    return __builtin_bit_cast(float, (u32)u << 16);
}

// -------- prep: W -> bf16 B-fragment layout --------------------------------
// Wf layout [kt(8)][nt(16)][lane(64)][j(8)]:
//   b[j] = W[kt*32 + (lane>>4)*8 + j][nt*16 + (lane&15)]
__global__ __launch_bounds__(256) void prep_kernel(
    const float* __restrict__ W, u16* __restrict__ Wf)
{
    const int t = blockIdx.x * 256 + threadIdx.x;  // 0..8191
    const int kt = t >> 10;
    const int nt = (t >> 6) & 15;
    const int lane = t & 63;
    const int kbase = kt * 32 + ((lane >> 4) * 8);
    const int n = nt * 16 + (lane & 15);
    u16 frag[8];
    #pragma unroll
    for (int j = 0; j < 8; ++j)
        frag[j] = f2bf(W[(size_t)(kbase + j) * D + n]);
    #pragma unroll
    for (int j = 0; j < 8; ++j)
        Wf[(size_t)t * 8 + j] = frag[j];
}

// -------- GEMM -------------------------------------------------------------
// One wave per 32-row tile, 2 row-halves x 16 col-tiles of 16x16x32.
// S stored as two column planes S[plane][row][128] bf16 (25.6 MB each).
__global__ __launch_bounds__(256) void gemm_kernel(
    const float* __restrict__ X, const u16* __restrict__ Wf,
    u16* __restrict__ S)
{
    const int lane = threadIdx.x & 63;
    const int tile = blockIdx.x * 4 + (threadIdx.x >> 6);
    if (tile >= GEMM_TILES) return;
    const int row0 = tile * 32;
    const int m = lane & 15;
    const int quad = lane >> 4;

    f32x4 acc0[16], acc1[16];
    #pragma unroll
    for (int t = 0; t < 16; ++t) {
        acc0[t] = (f32x4){0.f, 0.f, 0.f, 0.f};
        acc1[t] = (f32x4){0.f, 0.f, 0.f, 0.f};
    }

    const float* xA = X + (size_t)(row0 + m) * D + quad * 8;
    const float* xB = X + (size_t)(row0 + 16 + m) * D + quad * 8;
    const bf16x8* __restrict__ Bf = (const bf16x8*)Wf;

    for (int k0 = 0; k0 < 8; ++k0) {               // K-step = 32
        const float4 a0l = *(const float4*)(xA + k0 * 32);
        const float4 a0h = *(const float4*)(xA + k0 * 32 + 4);
        const float4 a1l = *(const float4*)(xB + k0 * 32);
        const float4 a1h = *(const float4*)(xB + k0 * 32 + 4);
        bf16x8 a0, a1;
        a0[0] = (short)f2bf(a0l.x); a0[1] = (short)f2bf(a0l.y);
        a0[2] = (short)f2bf(a0l.z); a0[3] = (short)f2bf(a0l.w);
        a0[4] = (short)f2bf(a0h.x); a0[5] = (short)f2bf(a0h.y);
        a0[6] = (short)f2bf(a0h.z); a0[7] = (short)f2bf(a0h.w);
        a1[0] = (short)f2bf(a1l.x); a1[1] = (short)f2bf(a1l.y);
        a1[2] = (short)f2bf(a1l.z); a1[3] = (short)f2bf(a1l.w);
        a1[4] = (short)f2bf(a1h.x); a1[5] = (short)f2bf(a1h.y);
        a1[6] = (short)f2bf(a1h.z); a1[7] = (short)f2bf(a1h.w);

        const bf16x8* bp = Bf + (size_t)k0 * 1024 + lane;
        #pragma unroll
        for (int g = 0; g < 4; ++g) {              // 4 col-tiles per group
            const bf16x8 b0 = bp[g * 256 + 0];
            const bf16x8 b1 = bp[g * 256 + 64];
            const bf16x8 b2 = bp[g * 256 + 128];
            const bf16x8 b3 = bp[g * 256 + 192];
            acc0[g*4+0] = __builtin_amdgcn_mfma_f32_16x16x32_bf16(a0, b0, acc0[g*4+0], 0, 0, 0);
            acc1[g*4+0] = __builtin_amdgcn_mfma_f32_16x16x32_bf16(a1, b0, acc1[g*4+0], 0, 0, 0);
            acc0[g*4+1] = __builtin_amdgcn_mfma_f32_16x16x32_bf16(a0, b1, acc0[g*4+1], 0, 0, 0);
            acc1[g*4+1] = __builtin_amdgcn_mfma_f32_16x16x32_bf16(a1, b1, acc1[g*4+1], 0, 0, 0);
            acc0[g*4+2] = __builtin_amdgcn_mfma_f32_16x16x32_bf16(a0, b2, acc0[g*4+2], 0, 0, 0);
            acc1[g*4+2] = __builtin_amdgcn_mfma_f32_16x16x32_bf16(a1, b2, acc1[g*4+2], 0, 0, 0);
            acc0[g*4+3] = __builtin_amdgcn_mfma_f32_16x16x32_bf16(a0, b3, acc0[g*4+3], 0, 0, 0);
            acc1[g*4+3] = __builtin_amdgcn_mfma_f32_16x16x32_bf16(a1, b3, acc1[g*4+3], 0, 0, 0);
        }
    }

    // C/D: col = nt*16 + m, row = quad*4 + i  (+16 for second half)
    // plane = nt>>3, in-plane col = (nt&7)*16 + m, plane row stride = 128
    #pragma unroll
    for (int nt = 0; nt < 16; ++nt) {
        u16* Sp = S + (size_t)(nt >> 3) * ((size_t)N_NODES * 128);
        const int cip = (nt & 7) * 16 + m;
        #pragma unroll
        for (int i = 0; i < 4; ++i) {
            Sp[(size_t)(row0 + quad * 4 + i) * 128 + cip]      = f2bf(acc0[nt][i]);
            Sp[(size_t)(row0 + 16 + quad * 4 + i) * 128 + cip] = f2bf(acc1[nt][i]);
        }
    }
}

// -------- hist2: per-partition bin histogram (LDS, no device atomics) ------
__global__ __launch_bounds__(512) void hist2_kernel(
    const int* __restrict__ row, u32* __restrict__ hcnt)
{
    __shared__ u32 h[NBIN];
    const int tid = threadIdx.x;
    const int p = blockIdx.x;
    for (int j = tid; j < NBIN; j += 512) h[j] = 0u;
    __syncthreads();
    const int e0 = p * EPP;
    for (int i = tid; i < EPP; i += 512)
        atomicAdd(&h[row[e0 + i] >> BIN_SHIFT], 1u);
    __syncthreads();
    u32* dst = hcnt + (size_t)p * NBIN;
    for (int j = tid; j < NBIN; j += 512) dst[j] = h[j];
}

// -------- binoffsets: per-bin exclusive scan over the 128 partitions -------
// In-place: hcnt[p][b] becomes poff[p][b] (exclusive within-bin offset of
// partition p). Thread p reads its own slot before overwriting it.
__global__ __launch_bounds__(128) void binoffsets_kernel(
    u32* __restrict__ hcnt, u32* __restrict__ coltot)
{
    __shared__ int w0tot;
    const int b = blockIdx.x;
    const int tid = threadIdx.x, lane = tid & 63, wv = tid >> 6;
    const int c = (int)hcnt[(size_t)tid * NBIN + b];
    int x = c;
    #pragma unroll
    for (int off = 1; off < 64; off <<= 1) {
        int y = __shfl_up(x, off);
        if (lane >= off) x += y;
    }
    if (tid == 63) w0tot = x;
    __syncthreads();
    const int excl = x - c + (wv ? w0tot : 0);
    hcnt[(size_t)tid * NBIN + b] = (u32)excl;
    if (tid == 127) coltot[b] = (u32)(excl + c);
}

// -------- binscan: sequential-carry wave scan of 1563 bin totals -----------
__global__ __launch_bounds__(64) void binscan_kernel(
    const u32* __restrict__ coltot, int* __restrict__ binstart,
    int* __restrict__ starts)
{
    const int tid = threadIdx.x;
    int carry = 0;
    for (int ch = 0; ch < (NBIN + 63) / 64; ++ch) {
        const int idx = ch * 64 + tid;
        const int c = (idx < NBIN) ? (int)coltot[idx] : 0;
        int x = c;
        #pragma unroll
        for (int off = 1; off < 64; off <<= 1) {
            int y = __shfl_up(x, off);
            if (tid >= off) x += y;
        }
        if (idx < NBIN) binstart[idx] = carry + x - c;
        carry += __shfl(x, 63);
    }
    if (tid == 0) {
        binstart[NBIN] = N_EDGES;
        starts[N_NODES] = N_EDGES;
    }
}

// -------- scatter1: deterministic atomic-free bucket scatter ---------------
// Block p's bin-b edges occupy the CONTIGUOUS slice
// [binstart[b]+poff[p][b], +cnt) -> each line written by (almost) exactly
// one block/XCD. This kills the 7.2x cross-XCD write amplification that
// the shared-frontier atomic scatter suffered (183 MB -> ~38 MB).
// Rank within slice via LDS cursor. Row low 6 bits packed above col.
__global__ __launch_bounds__(512) void scatter1_kernel(
    const int* __restrict__ row, const int* __restrict__ col,
    const float* __restrict__ val, const u32* __restrict__ poff,
    const int* __restrict__ binstart, uint2* __restrict__ pce)
{
    __shared__ int lcur[NBIN];
    const int tid = threadIdx.x;
    const int p = blockIdx.x;
    for (int b = tid; b < NBIN; b += 512)
        lcur[b] = binstart[b] + (int)poff[(size_t)p * NBIN + b];
    __syncthreads();
    const int e0 = p * EPP;
    for (int i = tid; i < EPP; i += 512) {
        const int e = e0 + i;
        const int r = row[e];
        const u32 c = (u32)col[e];
        const float v = val[e];
        const int pos = atomicAdd(&lcur[r >> BIN_SHIFT], 1);
        pce[pos] = make_uint2(c | ((u32)(r & (BIN_ROWS - 1)) << 17),
                              __builtin_bit_cast(u32, v));
    }
}

// -------- binsort: in-place per-bin row grouping + per-row starts ----------
// One block per 64-row bin (mean 2048 entries; BSORT_CAP=4096 is 45 sigma).
// Stage in LDS (all reads before any write -> in-place safe), count rows,
// wave-scan -> starts[], then scatter to exact row slots. The block fully
// rewrites its own region: block-exclusive lines, no write amplification.
__global__ __launch_bounds__(256) void binsort_kernel(
    const int* __restrict__ binstart, uint2* __restrict__ pce,
    int* __restrict__ starts)
{
    __shared__ uint2 ent[BSORT_CAP];
    __shared__ int rcnt[BIN_ROWS];
    __shared__ int rcur[BIN_ROWS];
    const int b = blockIdx.x;
    const int tid = threadIdx.x;
    const int base = binstart[b];
    const int n = binstart[b + 1] - base;
    if (tid < BIN_ROWS) rcnt[tid] = 0;
    __syncthreads();
    for (int i = tid; i < n; i += 256) {
        const uint2 e = pce[base + i];
        ent[i] = e;
        atomicAdd(&rcnt[(e.x >> 17) & (BIN_ROWS - 1)], 1);
    }
    __syncthreads();
    if (tid < BIN_ROWS) {
        const int c = rcnt[tid];
        int x = c;
        #pragma unroll
        for (int off = 1; off < 64; off <<= 1) {
            int y = __shfl_up(x, off);
            if (tid >= off) x += y;
        }
        const int excl = x - c;
        rcur[tid] = excl;
        const int r = b * BIN_ROWS + tid;
        if (r < N_NODES) starts[r] = base + excl;
    }
    __syncthreads();
    for (int i = tid; i < n; i += 256) {
        const uint2 e = ent[i];
        const int rl = (int)((e.x >> 17) & (u32)(BIN_ROWS - 1));
        const int pos = base + atomicAdd(&rcur[rl], 1);
        pce[pos] = make_uint2(e.x & 0x1FFFFu, e.y);
    }
}

// -------- segmented reduce: one wave/row, ONE COLUMN PLANE per launch ------
__global__ __launch_bounds__(256) void reduce_kernel(
    const u16* __restrict__ S, const int* __restrict__ starts,
    const uint2* __restrict__ pce, const float* __restrict__ bias,
    float* __restrict__ out, int plane)
{
    const int lane = threadIdx.x & 63;
    const int r = blockIdx.x * 4 + (threadIdx.x >> 6);
    const int s0 = starts[r];
    const int s1 = starts[r + 1];

    const u32* __restrict__ Sp =
        (const u32*)(S + (size_t)plane * ((size_t)N_NODES * 128));
    float2 acc = make_float2(0.f, 0.f);

    for (int base = s0; base < s1; base += 64) {
        const int n = min(64, s1 - base);
        uint2 pr = make_uint2(0u, 0u);
        if (lane < n) pr = pce[base + lane];
        const int c = (int)pr.x;
        const float v = __builtin_bit_cast(float, pr.y);

        int i = 0;
        for (; i + 8 <= n; i += 8) {
            int cc[8]; float vv[8]; u32 s[8];
            #pragma unroll
            for (int u = 0; u < 8; ++u) {
                cc[u] = __shfl(c, i + u);
                vv[u] = __shfl(v, i + u);
            }
            #pragma unroll
            for (int u = 0; u < 8; ++u)
                s[u] = Sp[(size_t)cc[u] * 64 + lane];
            #pragma unroll
            for (int u = 0; u < 8; ++u) {
                acc.x += vv[u] * bf2f((u16)(s[u] & 0xFFFFu));
                acc.y += vv[u] * bf2f((u16)(s[u] >> 16));
            }
        }
        for (; i < n; ++i) {
            const int c0 = __shfl(c, i);
            const float v0 = __shfl(v, i);
            const u32 a0 = Sp[(size_t)c0 * 64 + lane];
            acc.x += v0 * bf2f((u16)(a0 & 0xFFFFu));
            acc.y += v0 * bf2f((u16)(a0 >> 16));
        }
    }

    const float2 b2 = ((const float2*)bias)[plane * 64 + lane];
    acc.x += b2.x; acc.y += b2.y;
    ((float2*)out)[(size_t)r * 128 + plane * 64 + lane] = acc;
}

extern "C" void kernel_launch(void* const* d_in, const int* in_sizes, int n_in,
                              void* d_out, int out_size, void* d_ws, size_t ws_size,
                              hipStream_t stream) {
    const float* X    = (const float*)d_in[0];
    const int*   row  = (const int*)d_in[1];
    const int*   col  = (const int*)d_in[2];
    const float* val  = (const float*)d_in[3];
    const float* W    = (const float*)d_in[4];
    const float* bias = (const float*)d_in[5];
    float* out = (float*)d_out;

    // workspace layout (~78.1 MB; >=102.4 MB proven available)
    char* ws = (char*)d_ws;
    u16*   Sx      = (u16*)ws;                      // 51,200,000 B (2 planes)
    int*   starts  = (int*)(ws + 51200000);         //    400,064 B (N+1, padded)
    uint2* pce     = (uint2*)(ws + 51600064);       // 25,600,000 B (8-aligned)
    u16*   Wf      = (u16*)(ws + 77200064);         //    131,072 B (16-aligned)
    u32*   hcnt    = (u32*)(ws + 77331136);         //    800,256 B (128 x 1563)
    u32*   coltot  = (u32*)(ws + 78131392);         //      6,272 B
    int*   binstart= (int*)(ws + 78137664);         //      6,256 B (1564)

    // 1) prep: W -> bf16 B-fragment layout
    prep_kernel<<<WSH_BLOCKS, 256, 0, stream>>>(W, Wf);

    // 2) GEMM
    gemm_kernel<<<GEMM_BLOCKS, 256, 0, stream>>>(X, Wf, Sx);

    // 3) deterministic placement offsets (all atomic-free)
    hist2_kernel<<<P1, 512, 0, stream>>>(row, hcnt);
    binoffsets_kernel<<<NBIN, 128, 0, stream>>>(hcnt, coltot);
    binscan_kernel<<<1, 64, 0, stream>>>(coltot, binstart, starts);

    // 4) placement: deterministic scatter, then in-place bin sort (+starts)
    scatter1_kernel<<<P1, 512, 0, stream>>>(row, col, val, hcnt, binstart, pce);
    binsort_kernel<<<NBIN, 256, 0, stream>>>(binstart, pce, starts);

    // 5) segmented reduce, one 128-col plane per launch (L2-resident plane)
    reduce_kernel<<<N_NODES / 4, 256, 0, stream>>>(Sx, starts, pce, bias, out, 0);
    reduce_kernel<<<N_NODES / 4, 256, 0, stream>>>(Sx, starts, pce, bias, out, 1);
}

// Round 7
// 582.660 us; speedup vs baseline: 1.3801x; 1.0094x over previous
//
#include <hip/hip_runtime.h>

#define N_NODES 100000
#define N_EDGES 3200000
#define D 256
#define GEMM_TILES (N_NODES / 32)        // 3125 tiles of 32 rows
#define GEMM_BLOCKS ((GEMM_TILES + 3) / 4)  // 782
#define WSH_BLOCKS 32

#define BIN_SHIFT 6                      // 64 rows per bin
#define BIN_ROWS 64
#define NBIN 1563                        // ceil(100000/64)
#define P1 128                           // scatter partitions
#define EPP (N_EDGES / P1)               // 25000 edges per partition
#define BSORT_CAP 4096                   // LDS entries/bin (mean 2048, 45 sigma)

using u16 = unsigned short;
using u32 = unsigned int;

typedef __attribute__((ext_vector_type(8))) short bf16x8;
typedef __attribute__((ext_vector_type(4))) float f32x4;

__device__ inline u16 f2bf(float f) {
    u32 x = __builtin_bit_cast(u32, f);
    return (u16)((x + 0x7FFFu + ((x >> 16) & 1u)) >> 16);
}
__device__ inline float bf2f(u16 u) {
    return __builtin_bit_cast(float, (u32)u << 16);
}

// -------- prep: W -> bf16 B-fragment layout (round-4 exact) ----------------
// Wf layout [kt(8)][nt(16)][lane(64)][j(8)]:
//   b[j] = W[kt*32 + (lane>>4)*8 + j][nt*16 + (lane&15)]
__global__ __launch_bounds__(256) void prep_kernel(
    const float* __restrict__ W, u16* __restrict__ Wf)
{
    const int t = blockIdx.x * 256 + threadIdx.x;  // 0..8191
    const int kt = t >> 10;
    const int nt = (t >> 6) & 15;
    const int lane = t & 63;
    const int kbase = kt * 32 + ((lane >> 4) * 8);
    const int n = nt * 16 + (lane & 15);
    u16 frag[8];
    #pragma unroll
    for (int j = 0; j < 8; ++j)
        frag[j] = f2bf(W[(size_t)(kbase + j) * D + n]);
    #pragma unroll
    for (int j = 0; j < 8; ++j)
        Wf[(size_t)t * 8 + j] = frag[j];
}

// -------- hist2: per-partition bin histogram (round-4 exact) ---------------
__global__ __launch_bounds__(512) void hist2_kernel(
    const int* __restrict__ row, u32* __restrict__ hcnt)
{
    __shared__ u32 h[NBIN];
    const int tid = threadIdx.x;
    const int p = blockIdx.x;
    for (int j = tid; j < NBIN; j += 512) h[j] = 0u;
    __syncthreads();
    const int e0 = p * EPP;
    for (int i = tid; i < EPP; i += 512)
        atomicAdd(&h[row[e0 + i] >> BIN_SHIFT], 1u);
    __syncthreads();
    u32* dst = hcnt + (size_t)p * NBIN;
    for (int j = tid; j < NBIN; j += 512) dst[j] = h[j];
}

// -------- binoffsets: per-bin exclusive scan over partitions (round-4) -----
// In-place: hcnt[p][b] becomes poff[p][b] (exclusive within-bin offset).
__global__ __launch_bounds__(128) void binoffsets_kernel(
    u32* __restrict__ hcnt, u32* __restrict__ coltot)
{
    __shared__ int w0tot;
    const int b = blockIdx.x;
    const int tid = threadIdx.x, lane = tid & 63, wv = tid >> 6;
    const int c = (int)hcnt[(size_t)tid * NBIN + b];
    int x = c;
    #pragma unroll
    for (int off = 1; off < 64; off <<= 1) {
        int y = __shfl_up(x, off);
        if (lane >= off) x += y;
    }
    if (tid == 63) w0tot = x;
    __syncthreads();
    const int excl = x - c + (wv ? w0tot : 0);
    hcnt[(size_t)tid * NBIN + b] = (u32)excl;
    if (tid == 127) coltot[b] = (u32)(excl + c);
}

// -------- binscan: sequential-carry wave scan of bin totals (round-4) ------
__global__ __launch_bounds__(64) void binscan_kernel(
    const u32* __restrict__ coltot, int* __restrict__ binstart,
    int* __restrict__ starts)
{
    const int tid = threadIdx.x;
    int carry = 0;
    for (int ch = 0; ch < (NBIN + 63) / 64; ++ch) {
        const int idx = ch * 64 + tid;
        const int c = (idx < NBIN) ? (int)coltot[idx] : 0;
        int x = c;
        #pragma unroll
        for (int off = 1; off < 64; off <<= 1) {
            int y = __shfl_up(x, off);
            if (tid >= off) x += y;
        }
        if (idx < NBIN) binstart[idx] = carry + x - c;
        carry += __shfl(x, 63);
    }
    if (tid == 0) {
        binstart[NBIN] = N_EDGES;
        starts[N_NODES] = N_EDGES;
    }
}

// -------- fused GEMM + deterministic scatter (ONLY structural change) ------
// Both bodies are byte-identical to round 4 (which passed); the scatter
// branch's loop strides change 512->256 to match the uniform block size.
// No data overlap: GEMM reads X/Wf, writes S; scatter reads row/col/val/
// poff/binstart, writes pce. Co-scheduling hides the latency-bound scatter
// (128 blocks) under the MFMA-bound GEMM instead of running it serially.
__global__ __launch_bounds__(256) void gemm_scatter_kernel(
    const float* __restrict__ X, const u16* __restrict__ Wf,
    u16* __restrict__ S,
    const int* __restrict__ row, const int* __restrict__ col,
    const float* __restrict__ val, const u32* __restrict__ poff,
    const int* __restrict__ binstart, uint2* __restrict__ pce)
{
    if (blockIdx.x >= GEMM_BLOCKS) {
        __shared__ int lcur[NBIN];
        const int tid = threadIdx.x;
        const int p = blockIdx.x - GEMM_BLOCKS;
        for (int b = tid; b < NBIN; b += 256)
            lcur[b] = binstart[b] + (int)poff[(size_t)p * NBIN + b];
        __syncthreads();
        const int e0 = p * EPP;
        for (int i = tid; i < EPP; i += 256) {
            const int e = e0 + i;
            const int r = row[e];
            const u32 c = (u32)col[e];
            const float v = val[e];
            const int pos = atomicAdd(&lcur[r >> BIN_SHIFT], 1);
            pce[pos] = make_uint2(c | ((u32)(r & (BIN_ROWS - 1)) << 17),
                                  __builtin_bit_cast(u32, v));
        }
        return;
    }

    const int lane = threadIdx.x & 63;
    const int tile = blockIdx.x * 4 + (threadIdx.x >> 6);
    if (tile >= GEMM_TILES) return;
    const int row0 = tile * 32;
    const int m = lane & 15;
    const int quad = lane >> 4;

    f32x4 acc0[16], acc1[16];
    #pragma unroll
    for (int t = 0; t < 16; ++t) {
        acc0[t] = (f32x4){0.f, 0.f, 0.f, 0.f};
        acc1[t] = (f32x4){0.f, 0.f, 0.f, 0.f};
    }

    const float* xA = X + (size_t)(row0 + m) * D + quad * 8;
    const float* xB = X + (size_t)(row0 + 16 + m) * D + quad * 8;
    const bf16x8* __restrict__ Bf = (const bf16x8*)Wf;

    for (int k0 = 0; k0 < 8; ++k0) {               // K-step = 32
        const float4 a0l = *(const float4*)(xA + k0 * 32);
        const float4 a0h = *(const float4*)(xA + k0 * 32 + 4);
        const float4 a1l = *(const float4*)(xB + k0 * 32);
        const float4 a1h = *(const float4*)(xB + k0 * 32 + 4);
        bf16x8 a0, a1;
        a0[0] = (short)f2bf(a0l.x); a0[1] = (short)f2bf(a0l.y);
        a0[2] = (short)f2bf(a0l.z); a0[3] = (short)f2bf(a0l.w);
        a0[4] = (short)f2bf(a0h.x); a0[5] = (short)f2bf(a0h.y);
        a0[6] = (short)f2bf(a0h.z); a0[7] = (short)f2bf(a0h.w);
        a1[0] = (short)f2bf(a1l.x); a1[1] = (short)f2bf(a1l.y);
        a1[2] = (short)f2bf(a1l.z); a1[3] = (short)f2bf(a1l.w);
        a1[4] = (short)f2bf(a1h.x); a1[5] = (short)f2bf(a1h.y);
        a1[6] = (short)f2bf(a1h.z); a1[7] = (short)f2bf(a1h.w);

        const bf16x8* bp = Bf + (size_t)k0 * 1024 + lane;
        #pragma unroll
        for (int g = 0; g < 4; ++g) {              // 4 col-tiles per group
            const bf16x8 b0 = bp[g * 256 + 0];
            const bf16x8 b1 = bp[g * 256 + 64];
            const bf16x8 b2 = bp[g * 256 + 128];
            const bf16x8 b3 = bp[g * 256 + 192];
            acc0[g*4+0] = __builtin_amdgcn_mfma_f32_16x16x32_bf16(a0, b0, acc0[g*4+0], 0, 0, 0);
            acc1[g*4+0] = __builtin_amdgcn_mfma_f32_16x16x32_bf16(a1, b0, acc1[g*4+0], 0, 0, 0);
            acc0[g*4+1] = __builtin_amdgcn_mfma_f32_16x16x32_bf16(a0, b1, acc0[g*4+1], 0, 0, 0);
            acc1[g*4+1] = __builtin_amdgcn_mfma_f32_16x16x32_bf16(a1, b1, acc1[g*4+1], 0, 0, 0);
            acc0[g*4+2] = __builtin_amdgcn_mfma_f32_16x16x32_bf16(a0, b2, acc0[g*4+2], 0, 0, 0);
            acc1[g*4+2] = __builtin_amdgcn_mfma_f32_16x16x32_bf16(a1, b2, acc1[g*4+2], 0, 0, 0);
            acc0[g*4+3] = __builtin_amdgcn_mfma_f32_16x16x32_bf16(a0, b3, acc0[g*4+3], 0, 0, 0);
            acc1[g*4+3] = __builtin_amdgcn_mfma_f32_16x16x32_bf16(a1, b3, acc1[g*4+3], 0, 0, 0);
        }
    }

    // C/D: col = nt*16 + m, row = quad*4 + i  (+16 for second half)
    // plane = nt>>3, in-plane col = (nt&7)*16 + m, plane row stride = 128
    #pragma unroll
    for (int nt = 0; nt < 16; ++nt) {
        u16* Sp = S + (size_t)(nt >> 3) * ((size_t)N_NODES * 128);
        const int cip = (nt & 7) * 16 + m;
        #pragma unroll
        for (int i = 0; i < 4; ++i) {
            Sp[(size_t)(row0 + quad * 4 + i) * 128 + cip]      = f2bf(acc0[nt][i]);
            Sp[(size_t)(row0 + 16 + quad * 4 + i) * 128 + cip] = f2bf(acc1[nt][i]);
        }
    }
}

// -------- binsort: in-place per-bin row grouping + per-row starts (r4) -----
__global__ __launch_bounds__(256) void binsort_kernel(
    const int* __restrict__ binstart, uint2* __restrict__ pce,
    int* __restrict__ starts)
{
    __shared__ uint2 ent[BSORT_CAP];
    __shared__ int rcnt[BIN_ROWS];
    __shared__ int rcur[BIN_ROWS];
    const int b = blockIdx.x;
    const int tid = threadIdx.x;
    const int base = binstart[b];
    const int n = binstart[b + 1] - base;
    if (tid < BIN_ROWS) rcnt[tid] = 0;
    __syncthreads();
    for (int i = tid; i < n; i += 256) {
        const uint2 e = pce[base + i];
        ent[i] = e;
        atomicAdd(&rcnt[(e.x >> 17) & (BIN_ROWS - 1)], 1);
    }
    __syncthreads();
    if (tid < BIN_ROWS) {
        const int c = rcnt[tid];
        int x = c;
        #pragma unroll
        for (int off = 1; off < 64; off <<= 1) {
            int y = __shfl_up(x, off);
            if (tid >= off) x += y;
        }
        const int excl = x - c;
        rcur[tid] = excl;
        const int r = b * BIN_ROWS + tid;
        if (r < N_NODES) starts[r] = base + excl;
    }
    __syncthreads();
    for (int i = tid; i < n; i += 256) {
        const uint2 e = ent[i];
        const int rl = (int)((e.x >> 17) & (u32)(BIN_ROWS - 1));
        const int pos = base + atomicAdd(&rcur[rl], 1);
        pce[pos] = make_uint2(e.x & 0x1FFFFu, e.y);
    }
}

// -------- segmented reduce (round-4 exact, no nontemporal) -----------------
__global__ __launch_bounds__(256) void reduce_kernel(
    const u16* __restrict__ S, const int* __restrict__ starts,
    const uint2* __restrict__ pce, const float* __restrict__ bias,
    float* __restrict__ out, int plane)
{
    const int lane = threadIdx.x & 63;
    const int r = blockIdx.x * 4 + (threadIdx.x >> 6);
    const int s0 = starts[r];
    const int s1 = starts[r + 1];

    const u32* __restrict__ Sp =
        (const u32*)(S + (size_t)plane * ((size_t)N_NODES * 128));
    float2 acc = make_float2(0.f, 0.f);

    for (int base = s0; base < s1; base += 64) {
        const int n = min(64, s1 - base);
        uint2 pr = make_uint2(0u, 0u);
        if (lane < n) pr = pce[base + lane];
        const int c = (int)pr.x;
        const float v = __builtin_bit_cast(float, pr.y);

        int i = 0;
        for (; i + 8 <= n; i += 8) {
            int cc[8]; float vv[8]; u32 s[8];
            #pragma unroll
            for (int u = 0; u < 8; ++u) {
                cc[u] = __shfl(c, i + u);
                vv[u] = __shfl(v, i + u);
            }
            #pragma unroll
            for (int u = 0; u < 8; ++u)
                s[u] = Sp[(size_t)cc[u] * 64 + lane];
            #pragma unroll
            for (int u = 0; u < 8; ++u) {
                acc.x += vv[u] * bf2f((u16)(s[u] & 0xFFFFu));
                acc.y += vv[u] * bf2f((u16)(s[u] >> 16));
            }
        }
        for (; i < n; ++i) {
            const int c0 = __shfl(c, i);
            const float v0 = __shfl(v, i);
            const u32 a0 = Sp[(size_t)c0 * 64 + lane];
            acc.x += v0 * bf2f((u16)(a0 & 0xFFFFu));
            acc.y += v0 * bf2f((u16)(a0 >> 16));
        }
    }

    const float2 b2 = ((const float2*)bias)[plane * 64 + lane];
    acc.x += b2.x; acc.y += b2.y;
    ((float2*)out)[(size_t)r * 128 + plane * 64 + lane] = acc;
}

extern "C" void kernel_launch(void* const* d_in, const int* in_sizes, int n_in,
                              void* d_out, int out_size, void* d_ws, size_t ws_size,
                              hipStream_t stream) {
    const float* X    = (const float*)d_in[0];
    const int*   row  = (const int*)d_in[1];
    const int*   col  = (const int*)d_in[2];
    const float* val  = (const float*)d_in[3];
    const float* W    = (const float*)d_in[4];
    const float* bias = (const float*)d_in[5];
    float* out = (float*)d_out;

    // workspace layout (~78.1 MB; >=102.4 MB proven available)
    char* ws = (char*)d_ws;
    u16*   Sx      = (u16*)ws;                      // 51,200,000 B (2 planes)
    int*   starts  = (int*)(ws + 51200000);         //    400,064 B (N+1, padded)
    uint2* pce     = (uint2*)(ws + 51600064);       // 25,600,000 B (8-aligned)
    u16*   Wf      = (u16*)(ws + 77200064);         //    131,072 B (16-aligned)
    u32*   hcnt    = (u32*)(ws + 77331136);         //    800,256 B (128 x 1563)
    u32*   coltot  = (u32*)(ws + 78131392);         //      6,272 B
    int*   binstart= (int*)(ws + 78137664);         //      6,256 B (1564)

    // 1) prep: W -> bf16 B-fragment layout
    prep_kernel<<<WSH_BLOCKS, 256, 0, stream>>>(W, Wf);

    // 2) deterministic placement offsets (atomic-free)
    hist2_kernel<<<P1, 512, 0, stream>>>(row, hcnt);
    binoffsets_kernel<<<NBIN, 128, 0, stream>>>(hcnt, coltot);
    binscan_kernel<<<1, 64, 0, stream>>>(coltot, binstart, starts);

    // 3) fused GEMM + deterministic scatter (independent, co-scheduled)
    gemm_scatter_kernel<<<GEMM_BLOCKS + P1, 256, 0, stream>>>(
        X, Wf, Sx, row, col, val, hcnt, binstart, pce);

    // 4) in-place bin sort (+ per-row starts)
    binsort_kernel<<<NBIN, 256, 0, stream>>>(binstart, pce, starts);

    // 5) segmented reduce, one 128-col plane per launch (L2-resident plane)
    reduce_kernel<<<N_NODES / 4, 256, 0, stream>>>(Sx, starts, pce, bias, out, 0);
    reduce_kernel<<<N_NODES / 4, 256, 0, stream>>>(Sx, starts, pce, bias, out, 1);
}